// Round 13
// baseline (546.805 us; speedup 1.0000x reference)
//
#include <hip/hip_runtime.h>
#include <hip/hip_fp16.h>

// Problem constants (fixed by the harness' setup_inputs):
//   B=1000, L=50, D=128, NUM_ITEM=100000, NBIN=10, T=25500, n_edges=51000
#define D    128
#define L    50
#define G3   384          // 3*D
#define NBIN 10
#define NNMAX 25600       // graph nodes (25500) upper bound for LDS CSR build

// final-matmul tile params
#define FBM 128
#define FBN 128

typedef float f32x4 __attribute__((ext_vector_type(4)));
typedef short s16x8 __attribute__((ext_vector_type(8)));

#define MFMA_B16(a,b,c) __builtin_amdgcn_mfma_f32_16x16x32_bf16(a,b,c,0,0,0)

__device__ __forceinline__ float sigm(float x){ return 1.f/(1.f+__expf(-x)); }
__device__ __forceinline__ float tanh_fast(float x){
  float xx = fminf(fmaxf(x,-15.f),15.f);
  float e  = __expf(2.f*xx);
  return (e-1.f)/(e+1.f);
}

// split fp32 -> (hi bf16, lo bf16): x ~= hi + lo to ~2^-17 rel
#define SPLIT1(x, hu, lu) { unsigned u_ = __float_as_uint(x); hu = u_ >> 16; \
  float hf_ = __uint_as_float(u_ & 0xffff0000u); float lf_ = (x) - hf_; \
  lu = __float_as_uint(lf_) >> 16; }

__device__ __forceinline__ void split8(f32x4 a, f32x4 b, s16x8& hi, s16x8& lo){
  s16x8 h, l;
#pragma unroll
  for (int i=0;i<4;++i){
    unsigned hu, lu;
    SPLIT1(a[i], hu, lu)
    h[i] = (short)hu; l[i] = (short)lu;
  }
#pragma unroll
  for (int i=0;i<4;++i){
    unsigned hu, lu;
    SPLIT1(b[i], hu, lu)
    h[4+i] = (short)hu; l[4+i] = (short)lu;
  }
  hi = h; lo = l;
}

// ---------------- mega prep: tables + h0 init + zeros + tokmap + packed-A zero ----------------
__global__ void k_prep(const float* __restrict__ bin_emb,
                       const float* __restrict__ Wf, const float* __restrict__ bf,
                       const float* __restrict__ Wb, const float* __restrict__ bb,
                       const float* __restrict__ item_emb, const int* __restrict__ items,
                       float* __restrict__ tabf, float* __restrict__ tabb,
                       float* __restrict__ accA, float* __restrict__ xB,
                       float* __restrict__ cpad, int* __restrict__ tokmap,
                       unsigned short* __restrict__ zhi, unsigned short* __restrict__ zlo,
                       long long NG, long long BLD, int BL){
  const long long r1 = 7680, r2 = r1 + NG, r3 = r2 + BLD, r4 = r3 + BL;
  const long long ZP = 1024*128;           // packed A rows buffer (zero ALL; k_grus fills valid)
  const long long total = r4 + 2*ZP;
  for (long long i = (long long)blockIdx.x*256 + threadIdx.x; i < total;
       i += (long long)gridDim.x*256){
    if (i < r1){
      int id = (int)i; int dirr = id / (NBIN*G3); int rr = id % (NBIN*G3);
      int v = rr / G3, g = rr % G3;
      const float* W  = dirr ? Wb : Wf;
      const float* bi = dirr ? bb : bf;
      float a = bi[g];
      for (int d = 0; d < D; ++d) a += bin_emb[v*D+d]*W[g*D+d];
      (dirr ? tabb : tabf)[v*G3+g] = a;
    } else if (i < r2){
      long long k = i - r1;
      int nn = (int)(k>>7), d = (int)(k&127);
      float v = item_emb[(size_t)items[nn]*D + d];
      accA[k] = v; xB[k] = v;
    } else if (i < r3){
      cpad[i - r2] = 0.f;
    } else if (i < r4){
      tokmap[i - r3] = -1;
    } else {
      long long k = i - r4;
      if (k < ZP) zhi[k] = 0;
      else        zlo[k - ZP] = 0;
    }
  }
}

// ---------------- CSR: count + scan + fill in ONE single-block kernel (deg/cursor in LDS) ----------------
__global__ __launch_bounds__(1024) void k_csr1(const int* __restrict__ src,
                                               const int* __restrict__ dst,
                                               const float* __restrict__ ew,
                                               int* __restrict__ off,
                                               int* __restrict__ csrs, float* __restrict__ csrw,
                                               int nn, int ne){
  __shared__ int degs[NNMAX];    // 102 KB (deg -> cursor)
  __shared__ int part[1024];     // 4 KB
  int tid = threadIdx.x;
  for (int i = tid; i < nn; i += 1024) degs[i] = 0;
  __syncthreads();
  for (int e = tid; e < ne; e += 1024) atomicAdd(&degs[dst[e]], 1);
  __syncthreads();
  int chunk = (nn + 1023) >> 10;
  int c0 = tid*chunk;
  int s = 0;
  for (int k = 0; k < chunk; ++k){ int v = c0+k; if (v < nn) s += degs[v]; }
  part[tid] = s; __syncthreads();
  for (int d = 1; d < 1024; d <<= 1){
    int v = (tid >= d) ? part[tid-d] : 0;
    __syncthreads();
    part[tid] += v;
    __syncthreads();
  }
  int run = part[tid] - s;       // exclusive base
  for (int k = 0; k < chunk; ++k){
    int v = c0+k;
    if (v < nn){
      off[v] = run;
      int dv = degs[v];
      degs[v] = run;             // becomes cursor
      run += dv;
    }
  }
  if (tid == 1023) off[nn] = part[1023];
  __syncthreads();
  // fill (cursors in LDS)
  for (int e = tid; e < ne; e += 1024){
    int p = atomicAdd(&degs[dst[e]], 1);
    csrs[p] = src[e];
    csrw[p] = ew[e];
  }
}

// gather-based propagation layer: xn[v] = sum_in x[src]*w; acc += xn
__global__ void k_gath(const float* __restrict__ x, float* __restrict__ xn,
                       float* __restrict__ acc,
                       const int* __restrict__ off, const int* __restrict__ csrs,
                       const float* __restrict__ csrw, int n){
  int i = blockIdx.x*256 + threadIdx.x;
  if (i >= n) return;
  int v = i >> 7, d = i & (D-1);
  int a = off[v], b = off[v+1];
  float s = 0.f;
  for (int k = a; k < b; ++k)
    s += x[(size_t)csrs[k]*D + d] * csrw[k];
  xn[i] = s;
  acc[i] += s;
}

// ============ MFMA GRU: double-buffered h (1 barrier/step), 2-way split chains ============
__global__ __launch_bounds__(512) void k_gru_fb(
    const float* __restrict__ Whh_f, const float* __restrict__ Whh_b,
    const float* __restrict__ bhh_f, const float* __restrict__ bhh_b,
    const float* __restrict__ tabf,  const float* __restrict__ tabb,
    const int*   __restrict__ bins,  int Bn,
    float* __restrict__ outf, float* __restrict__ outbrev){
  const int dir = blockIdx.y;
  const int b0  = blockIdx.x * 16;
  const float* Whh = dir ? Whh_b : Whh_f;
  const float* bhh = dir ? bhh_b : bhh_f;
  const float* tab = dir ? tabb  : tabf;
  float* outp = dir ? outbrev : outf;

  __shared__ unsigned short hhi[2*16*128];   // 8 KB double-buffered, swizzled [sess][j]
  __shared__ unsigned short hlo[2*16*128];   // 8 KB
  __shared__ float xts[NBIN*G3];             // 15 KB
  __shared__ int   binr[16][L];

  const int tid = threadIdx.x;
  const int wv = tid>>6, lane = tid&63;
  const int l15 = lane&15, lk = lane>>4;
  const int jb = wv*16;
  const int jq = jb + lk*4;               // first of this thread's 4 j's

  s16x8 whi[3][4], wlo[3][4];
#pragma unroll
  for (int g3i = 0; g3i < 3; ++g3i)
#pragma unroll
    for (int ks = 0; ks < 4; ++ks){
      const f32x4* s = (const f32x4*)&Whh[(size_t)(g3i*D + jb + l15)*D + ks*32 + lk*8];
      split8(s[0], s[1], whi[g3i][ks], wlo[g3i][ks]);
    }
  f32x4 bhv[3];
#pragma unroll
  for (int g3i = 0; g3i < 3; ++g3i) bhv[g3i] = *(const f32x4*)&bhh[g3i*D + jq];

  for (int i = tid; i < NBIN*G3; i += 512) xts[i] = tab[i];
  for (int i = tid; i < 16*L; i += 512){
    int r = i / L, t = i % L;
    binr[r][t] = (b0 + r < Bn) ? bins[(b0+r)*L + (dir ? (L-1-t) : t)] : 0;
  }
  for (int i = tid; i < 2*16*128; i += 512){ hhi[i] = 0; hlo[i] = 0; }

  const int sess = l15;
  const bool sv = (b0 + sess) < Bn;
  float hreg[4] = {0.f,0.f,0.f,0.f};
  const int wbyte = sess*256 + (((jq>>3) ^ (sess&7))<<4) + ((jq&7)<<1);
  int cur = 0;
  __syncthreads();

  for (int t = 0; t < L; ++t){
    f32x4 c0a={0.f,0.f,0.f,0.f}, c1a=c0a, c2a=c0a, c0b=c0a, c1b=c0a, c2b=c0a;
    const int rb = cur*4096;
#pragma unroll
    for (int ks = 0; ks < 2; ++ks){
      int off = rb + l15*256 + ((((ks<<2)+lk) ^ (l15&7)) << 4);
      s16x8 bh8 = *(const s16x8*)((const char*)hhi + off);
      s16x8 bl8 = *(const s16x8*)((const char*)hlo + off);
      c0a = MFMA_B16(whi[0][ks], bh8, c0a); c0a = MFMA_B16(whi[0][ks], bl8, c0a); c0a = MFMA_B16(wlo[0][ks], bh8, c0a);
      c1a = MFMA_B16(whi[1][ks], bh8, c1a); c1a = MFMA_B16(whi[1][ks], bl8, c1a); c1a = MFMA_B16(wlo[1][ks], bh8, c1a);
      c2a = MFMA_B16(whi[2][ks], bh8, c2a); c2a = MFMA_B16(whi[2][ks], bl8, c2a); c2a = MFMA_B16(wlo[2][ks], bh8, c2a);
    }
#pragma unroll
    for (int ks = 2; ks < 4; ++ks){
      int off = rb + l15*256 + ((((ks<<2)+lk) ^ (l15&7)) << 4);
      s16x8 bh8 = *(const s16x8*)((const char*)hhi + off);
      s16x8 bl8 = *(const s16x8*)((const char*)hlo + off);
      c0b = MFMA_B16(whi[0][ks], bh8, c0b); c0b = MFMA_B16(whi[0][ks], bl8, c0b); c0b = MFMA_B16(wlo[0][ks], bh8, c0b);
      c1b = MFMA_B16(whi[1][ks], bh8, c1b); c1b = MFMA_B16(whi[1][ks], bl8, c1b); c1b = MFMA_B16(wlo[1][ks], bh8, c1b);
      c2b = MFMA_B16(whi[2][ks], bh8, c2b); c2b = MFMA_B16(whi[2][ks], bl8, c2b); c2b = MFMA_B16(wlo[2][ks], bh8, c2b);
    }
    f32x4 c0 = c0a + c0b, c1 = c1a + c1b, c2 = c2a + c2b;
    int bin = binr[sess][t];
    const float* xb = &xts[bin*G3];
    f32x4 xr4 = *(const f32x4*)&xb[jq];
    f32x4 xz4 = *(const f32x4*)&xb[D + jq];
    f32x4 xn4 = *(const f32x4*)&xb[2*D + jq];
    ushort4 hi4, lo4;
    f32x4 hn4;
#pragma unroll
    for (int qq = 0; qq < 4; ++qq){
      float gr = c0[qq] + bhv[0][qq];
      float gz = c1[qq] + bhv[1][qq];
      float gn = c2[qq] + bhv[2][qq];
      float rr = sigm(xr4[qq] + gr);
      float zz = sigm(xz4[qq] + gz);
      float nn = tanh_fast(xn4[qq] + rr*gn);
      float hnew = (1.f-zz)*nn + zz*hreg[qq];
      hreg[qq] = hnew;
      unsigned hu, lu; SPLIT1(hnew, hu, lu)
      ((unsigned short*)&hi4)[qq] = (unsigned short)hu;
      ((unsigned short*)&lo4)[qq] = (unsigned short)lu;
      hn4[qq] = hnew;
    }
    int wb = (cur^1)*4096 + wbyte;
    *(ushort4*)((char*)hhi + wb) = hi4;
    *(ushort4*)((char*)hlo + wb) = lo4;
    if (sv){
      float4 o = make_float4(hn4[0],hn4[1],hn4[2],hn4[3]);
      *(float4*)&outp[((size_t)(b0+sess)*L + (dir ? (L-1-t) : t))*D + jq] = o;
    }
    __syncthreads();
    cur ^= 1;
  }
}

// ---------------- FUSED attn: e_hat + beta + c  AND  xps = c @ Wih_s.T + bih_s ----------------
__global__ __launch_bounds__(512) void k_attn(
    const float* __restrict__ outf, const float* __restrict__ outbrev,
    const float* __restrict__ accA, const int* __restrict__ idxmap,
    const float* __restrict__ w1, const float* __restrict__ w2,
    const float* __restrict__ v3,
    const float* __restrict__ Wih, const float* __restrict__ bih,
    const int* __restrict__ seg, const int* __restrict__ pos, int T,
    float* __restrict__ c_pad, int* __restrict__ tokmap,
    float* __restrict__ xps){
  __shared__ unsigned short Bhi[32*256];   // 16 KB  beta-B [tok][K=256]; first 8KB reused for c-frags
  __shared__ unsigned short Blo[32*256];   // 16 KB
  __shared__ float us[32*388];             // 49.6 KB
  __shared__ float w1s[2*D];
  __shared__ float bihs[G3];
  __shared__ float betas[32];

  const int tid = threadIdx.x;
  const int wv = tid>>6, lane = tid&63;
  const int l15 = lane&15, lk = lane>>4;
  const int gbase = wv * 48;

  // loop-invariant w2 fragments (beta): wave wv owns u-cols [16wv,16wv+16), K=256 -> 8 ks
  s16x8 w2hi[8], w2lo[8];
#pragma unroll
  for (int ks = 0; ks < 8; ++ks){
    const f32x4* s = (const f32x4*)&w2[(size_t)(wv*16 + l15)*256 + ks*32 + lk*8];
    split8(s[0], s[1], w2hi[ks], w2lo[ks]);
  }
  f32x4 v3q = *(const f32x4*)&v3[wv*16 + lk*4];
  // loop-invariant Wih fragments (xps): wave wv owns 48 gates
  s16x8 whi[3][4], wlo[3][4];
#pragma unroll
  for (int mt = 0; mt < 3; ++mt)
#pragma unroll
    for (int ks = 0; ks < 4; ++ks){
      const f32x4* s = (const f32x4*)&Wih[(size_t)(gbase + mt*16 + l15)*D + ks*32 + lk*8];
      split8(s[0], s[1], whi[mt][ks], wlo[mt][ks]);
    }
  for (int i = tid; i < 2*D; i += 512) w1s[i] = w1[i];
  for (int i = tid; i < G3;  i += 512) bihs[i] = bih[i];
  __syncthreads();

  const int tok = tid >> 4;            // 0..31
  const int d0  = (tid & 15) * 8;      // this thread's 8 dims
  const int sw  = (tid & 15) ^ (tok & 7);
  const int ntiles = (T + 31) >> 5;

  for (int tile = blockIdx.x; tile < ntiles; tile += gridDim.x){
    int t = tile*32 + tok;
    bool valid = (t < T);
    // ---- phase 1: gather, gate, e_hat, stage beta-B
    int sp = 0;
    f32x4 ef0 = {0,0,0,0}, ef1 = ef0, eb0 = ef0, eb1 = ef0, hf0 = ef0, hf1 = ef0;
    if (valid){
      sp = seg[t]*L + pos[t];
      const f32x4* pf = (const f32x4*)&outf[(size_t)sp*D + d0];
      const f32x4* pb = (const f32x4*)&outbrev[(size_t)sp*D + d0];
      const f32x4* ph = (const f32x4*)&accA[(size_t)idxmap[t]*D + d0];
      ef0 = pf[0]; ef1 = pf[1];
      eb0 = pb[0]; eb1 = pb[1];
      hf0 = ph[0]; hf1 = ph[1];
#pragma unroll
      for (int k=0;k<4;++k){ hf0[k]*=0.25f; hf1[k]*=0.25f; }
    }
    float p = 0.f;
#pragma unroll
    for (int k=0;k<4;++k){
      p += ef0[k]*w1s[d0+k]     + eb0[k]*w1s[D+d0+k];
      p += ef1[k]*w1s[d0+4+k]   + eb1[k]*w1s[D+d0+4+k];
    }
    p += __shfl_xor(p,1); p += __shfl_xor(p,2);
    p += __shfl_xor(p,4); p += __shfl_xor(p,8);
    float gate = sigm(p);
    f32x4 eh0, eh1;
#pragma unroll
    for (int k=0;k<4;++k){
      eh0[k] = gate*ef0[k] + (1.f-gate)*eb0[k];
      eh1[k] = gate*ef1[k] + (1.f-gate)*eb1[k];
    }
    {
      s16x8 h8, l8;
      split8(hf0, hf1, h8, l8);
      int byte = tok*512 + (sw<<4);
      *(s16x8*)((char*)Bhi + byte) = h8;
      *(s16x8*)((char*)Blo + byte) = l8;
      split8(eh0, eh1, h8, l8);
      byte = tok*512 + ((16+sw)<<4);
      *(s16x8*)((char*)Bhi + byte) = h8;
      *(s16x8*)((char*)Blo + byte) = l8;
    }
    if (tid < 32) betas[tid] = 0.f;
    __syncthreads();
    // ---- phase 2: u = w2 @ B (split chains), tanh, v3 reduce
#pragma unroll
    for (int tt = 0; tt < 2; ++tt){
      f32x4 ca = {0.f,0.f,0.f,0.f}, cb = ca;
#pragma unroll
      for (int ks = 0; ks < 4; ++ks){
        int s_ = ((ks<<2)+lk);
        int off = (tt*16 + l15)*512 + ((s_ ^ (l15&7)) << 4);
        s16x8 bh8 = *(const s16x8*)((const char*)Bhi + off);
        s16x8 bl8 = *(const s16x8*)((const char*)Blo + off);
        ca = MFMA_B16(w2hi[ks], bh8, ca);
        ca = MFMA_B16(w2hi[ks], bl8, ca);
        ca = MFMA_B16(w2lo[ks], bh8, ca);
      }
#pragma unroll
      for (int ks = 4; ks < 8; ++ks){
        int s_ = ((ks<<2)+lk);
        int off = (tt*16 + l15)*512 + ((s_ ^ (l15&7)) << 4);
        s16x8 bh8 = *(const s16x8*)((const char*)Bhi + off);
        s16x8 bl8 = *(const s16x8*)((const char*)Blo + off);
        cb = MFMA_B16(w2hi[ks], bh8, cb);
        cb = MFMA_B16(w2hi[ks], bl8, cb);
        cb = MFMA_B16(w2lo[ks], bh8, cb);
      }
      f32x4 c = ca + cb;
      float pv = 0.f;
#pragma unroll
      for (int qq = 0; qq < 4; ++qq) pv += tanh_fast(c[qq]) * v3q[qq];
      pv += __shfl_xor(pv, 16);
      pv += __shfl_xor(pv, 32);
      if (lk == 0) atomicAdd(&betas[tt*16 + l15], pv);
    }
    __syncthreads();
    // ---- phase 3: c = beta*hf (regs) -> cpad + stage c-frags (xps layout, reuse Bhi/Blo)
    f32x4 c0v = {0,0,0,0}, c1v = c0v;
    if (valid){
      float beta = betas[tok];
#pragma unroll
      for (int k=0;k<4;++k){ c0v[k] = beta*hf0[k]; c1v[k] = beta*hf1[k]; }
      f32x4* pc = (f32x4*)&c_pad[(size_t)sp*D + d0];
      pc[0] = c0v; pc[1] = c1v;
      if ((tid & 15) == 0) tokmap[sp] = t;
    }
    {
      s16x8 h8, l8;
      split8(c0v, c1v, h8, l8);
      int byte = tok*256 + (sw<<4);
      *(s16x8*)((char*)Bhi + byte) = h8;
      *(s16x8*)((char*)Blo + byte) = l8;
    }
    __syncthreads();
    // ---- phase 4: xps MFMA (split chains) -> us
#pragma unroll
    for (int tt = 0; tt < 2; ++tt){
      f32x4 ca[3], cb[3];
#pragma unroll
      for (int mt = 0; mt < 3; ++mt){ f32x4 z = {0,0,0,0}; ca[mt] = z; cb[mt] = z; }
#pragma unroll
      for (int ks = 0; ks < 2; ++ks){
        int off = (tt*16 + l15)*256 + ((((ks<<2)+lk) ^ (l15&7)) << 4);
        s16x8 bh8 = *(const s16x8*)((const char*)Bhi + off);
        s16x8 bl8 = *(const s16x8*)((const char*)Blo + off);
        ca[0] = MFMA_B16(whi[0][ks], bh8, ca[0]); ca[0] = MFMA_B16(whi[0][ks], bl8, ca[0]); ca[0] = MFMA_B16(wlo[0][ks], bh8, ca[0]);
        ca[1] = MFMA_B16(whi[1][ks], bh8, ca[1]); ca[1] = MFMA_B16(whi[1][ks], bl8, ca[1]); ca[1] = MFMA_B16(wlo[1][ks], bh8, ca[1]);
        ca[2] = MFMA_B16(whi[2][ks], bh8, ca[2]); ca[2] = MFMA_B16(whi[2][ks], bl8, ca[2]); ca[2] = MFMA_B16(wlo[2][ks], bh8, ca[2]);
      }
#pragma unroll
      for (int ks = 2; ks < 4; ++ks){
        int off = (tt*16 + l15)*256 + ((((ks<<2)+lk) ^ (l15&7)) << 4);
        s16x8 bh8 = *(const s16x8*)((const char*)Bhi + off);
        s16x8 bl8 = *(const s16x8*)((const char*)Blo + off);
        cb[0] = MFMA_B16(whi[0][ks], bh8, cb[0]); cb[0] = MFMA_B16(whi[0][ks], bl8, cb[0]); cb[0] = MFMA_B16(wlo[0][ks], bh8, cb[0]);
        cb[1] = MFMA_B16(whi[1][ks], bh8, cb[1]); cb[1] = MFMA_B16(whi[1][ks], bl8, cb[1]); cb[1] = MFMA_B16(wlo[1][ks], bh8, cb[1]);
        cb[2] = MFMA_B16(whi[2][ks], bh8, cb[2]); cb[2] = MFMA_B16(whi[2][ks], bl8, cb[2]); cb[2] = MFMA_B16(wlo[2][ks], bh8, cb[2]);
      }
#pragma unroll
      for (int mt = 0; mt < 3; ++mt){
        f32x4 c = ca[mt] + cb[mt];
        *(f32x4*)&us[(tt*16 + l15)*388 + gbase + mt*16 + lk*4] = c;
      }
    }
    __syncthreads();
    // ---- phase 5: coalesced xps write (+bias)
    for (int i4 = tid; i4 < 32*96; i4 += 512){
      int tk = i4 / 96, g4 = (i4 % 96) * 4;
      int tt2 = tile*32 + tk;
      if (tt2 < T){
        f32x4 u4 = *(const f32x4*)&us[tk*388 + g4];
        f32x4 b4 = *(const f32x4*)&bihs[g4];
#pragma unroll
        for (int k=0;k<4;++k) u4[k] += b4[k];
        *(f32x4*)&xps[(size_t)tt2*G3 + g4] = u4;
      }
    }
    __syncthreads();
  }
}

// ---------------- short GRU (dbuf h, split chains) + final gate (zl from cpad) -> packed z;
//                  idle blocks (>= nGru) run the emb fragment-pack ----------------
__global__ __launch_bounds__(512) void k_grus(
    const float* __restrict__ Whh, const float* __restrict__ bhh,
    const float* __restrict__ bih,
    const float* __restrict__ xps, const int* __restrict__ tokmap,
    const float* __restrict__ c_pad, const float* __restrict__ w3,
    const float* __restrict__ b3, int Bn,
    unsigned short* __restrict__ zhi, unsigned short* __restrict__ zlo,
    const float* __restrict__ emb,
    unsigned short* __restrict__ ehp, unsigned short* __restrict__ elp,
    int NI, int nslots, int nGru){
  if (blockIdx.x >= nGru){
    int nb = gridDim.x - nGru;
    for (int s = (blockIdx.x - nGru)*512 + threadIdx.x; s < nslots; s += nb*512){
      int lane = s & 63;
      int nfw  = (s>>6) & 7;
      int kk   = (s>>9) & 3;
      int ntl  = s >> 11;
      int row  = ntl*128 + (nfw>>2)*64 + (nfw&3)*16 + (lane&15);
      int d0   = kk*32 + (lane>>4)*8;
      s16x8 h8 = {0,0,0,0,0,0,0,0}, l8 = h8;
      if (row < NI){
        const f32x4* src = (const f32x4*)&emb[(size_t)row*D + d0];
        split8(src[0], src[1], h8, l8);
      }
      *(s16x8*)&ehp[(size_t)s*8] = h8;
      *(s16x8*)&elp[(size_t)s*8] = l8;
    }
    return;
  }
  const int b0 = blockIdx.x * 16;

  __shared__ unsigned short hhi[2*16*128];
  __shared__ unsigned short hlo[2*16*128];
  __shared__ int   maprow[16][L];
  __shared__ float redg[16];

  const int tid = threadIdx.x;
  const int wv = tid>>6, lane = tid&63;
  const int l15 = lane&15, lk = lane>>4;
  const int jb = wv*16;
  const int jq = jb + lk*4;

  s16x8 whi[3][4], wlo[3][4];
#pragma unroll
  for (int g3i = 0; g3i < 3; ++g3i)
#pragma unroll
    for (int ks = 0; ks < 4; ++ks){
      const f32x4* s = (const f32x4*)&Whh[(size_t)(g3i*D + jb + l15)*D + ks*32 + lk*8];
      split8(s[0], s[1], whi[g3i][ks], wlo[g3i][ks]);
    }
  f32x4 bhv[3], biv[3];
#pragma unroll
  for (int g3i = 0; g3i < 3; ++g3i){
    bhv[g3i] = *(const f32x4*)&bhh[g3i*D + jq];
    biv[g3i] = *(const f32x4*)&bih[g3i*D + jq];
  }
  for (int i = tid; i < 16*L; i += 512){
    int r = i / L, t = i % L;
    maprow[r][t] = (b0 + r < Bn) ? tokmap[(b0+r)*L + t] : -1;
  }
  for (int i = tid; i < 2*16*128; i += 512){ hhi[i] = 0; hlo[i] = 0; }

  const int sess = l15;
  const bool sv = (b0 + sess) < Bn;
  float hreg[4] = {0.f,0.f,0.f,0.f};
  const int wbyte = sess*256 + (((jq>>3) ^ (sess&7))<<4) + ((jq&7)<<1);
  int cur = 0;
  __syncthreads();

  for (int t = 0; t < L; ++t){
    int tok = maprow[sess][t];
    f32x4 xr4, xz4, xn4;
    if (tok >= 0){
      const float* xb = &xps[(size_t)tok*G3];
      xr4 = *(const f32x4*)&xb[jq];
      xz4 = *(const f32x4*)&xb[D + jq];
      xn4 = *(const f32x4*)&xb[2*D + jq];
    } else { xr4 = biv[0]; xz4 = biv[1]; xn4 = biv[2]; }
    f32x4 c0a={0.f,0.f,0.f,0.f}, c1a=c0a, c2a=c0a, c0b=c0a, c1b=c0a, c2b=c0a;
    const int rb = cur*4096;
#pragma unroll
    for (int ks = 0; ks < 2; ++ks){
      int off = rb + l15*256 + ((((ks<<2)+lk) ^ (l15&7)) << 4);
      s16x8 bh8 = *(const s16x8*)((const char*)hhi + off);
      s16x8 bl8 = *(const s16x8*)((const char*)hlo + off);
      c0a = MFMA_B16(whi[0][ks], bh8, c0a); c0a = MFMA_B16(whi[0][ks], bl8, c0a); c0a = MFMA_B16(wlo[0][ks], bh8, c0a);
      c1a = MFMA_B16(whi[1][ks], bh8, c1a); c1a = MFMA_B16(whi[1][ks], bl8, c1a); c1a = MFMA_B16(wlo[1][ks], bh8, c1a);
      c2a = MFMA_B16(whi[2][ks], bh8, c2a); c2a = MFMA_B16(whi[2][ks], bl8, c2a); c2a = MFMA_B16(wlo[2][ks], bh8, c2a);
    }
#pragma unroll
    for (int ks = 2; ks < 4; ++ks){
      int off = rb + l15*256 + ((((ks<<2)+lk) ^ (l15&7)) << 4);
      s16x8 bh8 = *(const s16x8*)((const char*)hhi + off);
      s16x8 bl8 = *(const s16x8*)((const char*)hlo + off);
      c0b = MFMA_B16(whi[0][ks], bh8, c0b); c0b = MFMA_B16(whi[0][ks], bl8, c0b); c0b = MFMA_B16(wlo[0][ks], bh8, c0b);
      c1b = MFMA_B16(whi[1][ks], bh8, c1b); c1b = MFMA_B16(whi[1][ks], bl8, c1b); c1b = MFMA_B16(wlo[1][ks], bh8, c1b);
      c2b = MFMA_B16(whi[2][ks], bh8, c2b); c2b = MFMA_B16(whi[2][ks], bl8, c2b); c2b = MFMA_B16(wlo[2][ks], bh8, c2b);
    }
    f32x4 c0 = c0a + c0b, c1 = c1a + c1b, c2 = c2a + c2b;
    ushort4 hi4, lo4;
#pragma unroll
    for (int qq = 0; qq < 4; ++qq){
      float gr = c0[qq] + bhv[0][qq];
      float gz = c1[qq] + bhv[1][qq];
      float gn = c2[qq] + bhv[2][qq];
      float rr = sigm(xr4[qq] + gr);
      float zz = sigm(xz4[qq] + gz);
      float nn = tanh_fast(xn4[qq] + rr*gn);
      float hnew = (1.f-zz)*nn + zz*hreg[qq];
      hreg[qq] = hnew;
      unsigned hu, lu; SPLIT1(hnew, hu, lu)
      ((unsigned short*)&hi4)[qq] = (unsigned short)hu;
      ((unsigned short*)&lo4)[qq] = (unsigned short)lu;
    }
    int wb = (cur^1)*4096 + wbyte;
    *(ushort4*)((char*)hhi + wb) = hi4;
    *(ushort4*)((char*)hlo + wb) = lo4;
    __syncthreads();
    cur ^= 1;
  }

  // ---- fused final gate: zl computed directly from cpad; z stored PACKED
  if (tid < 16) redg[tid] = 0.f;
  __syncthreads();
  f32x4 zl4 = {0.f,0.f,0.f,0.f};
  if (sv){
    const size_t rowbase = (size_t)(b0+sess)*L;
    for (int l = 0; l < L; ++l)
      zl4 += *(const f32x4*)&c_pad[(rowbase + l)*D + jq];
  }
  f32x4 w34 = *(const f32x4*)&w3[jq];
  float part = 0.f;
#pragma unroll
  for (int qq = 0; qq < 4; ++qq) part += (zl4[qq] + hreg[qq]) * w34[qq];
  if (sv) atomicAdd(&redg[sess], part);
  __syncthreads();
  if (sv){
    float f = sigm(redg[sess] + b3[0]);
    ushort4 h4, l4;
#pragma unroll
    for (int qq = 0; qq < 4; ++qq){
      float zv = f*zl4[qq] + (1.f-f)*hreg[qq];
      unsigned hu, lu; SPLIT1(zv, hu, lu)
      ((unsigned short*)&h4)[qq] = (unsigned short)hu;
      ((unsigned short*)&l4)[qq] = (unsigned short)lu;
    }
    int row = b0 + sess;
    int mtile = row >> 7, r128 = row & 127;
    int wmr = r128 >> 6, mfr = (r128 >> 4) & 3, l15r = r128 & 15;
    int kkr = jq >> 5, lkr = (jq & 31) >> 3, e0 = jq & 7;
    int laner = lkr*16 + l15r;
    size_t slot = ((size_t)(((mtile*4 + kkr)*2 + wmr)*4 + mfr))*64 + laner;
    *(ushort4*)&zhi[slot*8 + e0] = h4;
    *(ushort4*)&zlo[slot*8 + e0] = l4;
  }
}

// ---------------- out = z @ emb.T  (fragment-major packed operands: 1KB contiguous loads) ----------------
__global__ __launch_bounds__(256, 3) void k_fmm(
    const unsigned short* __restrict__ zhi, const unsigned short* __restrict__ zlo,
    const unsigned short* __restrict__ ehp, const unsigned short* __restrict__ elp,
    float* __restrict__ out, int NI, int Bsz){
  __shared__ float fs[64*136];   // 34 KB epilogue staging

  int nwg = gridDim.x;
  int hw  = blockIdx.x;
  int q8 = nwg >> 3, r8 = nwg & 7;
  int xcd = hw & 7, idx = hw >> 3;
  int logical = (xcd < r8 ? xcd*(q8+1) : r8*(q8+1) + (xcd-r8)*q8) + idx;
  int ntile = logical >> 3;       // 8 consecutive logicals share an emb tile
  int mtile = logical & 7;
  int m0 = mtile*FBM;
  int n0 = ntile*FBN;

  const int t    = threadIdx.x;
  const int lane = t & 63;
  const int wid  = t >> 6;
  const int wm   = wid >> 1, wn = wid & 1;   // 2x2 wave grid, 64x64 each
  const int l15  = lane & 15, lk = lane >> 4;

  f32x4 acc[4][4];
#pragma unroll
  for (int i = 0; i < 4; ++i)
#pragma unroll
    for (int jj = 0; jj < 4; ++jj){ f32x4 z4 = {0.f,0.f,0.f,0.f}; acc[i][jj] = z4; }

#pragma unroll
  for (int kk = 0; kk < 4; ++kk){
    s16x8 ah[4], al[4], bh8[4], bl8[4];
#pragma unroll
    for (int mf = 0; mf < 4; ++mf){
      size_t slot = ((size_t)(((mtile*4 + kk)*2 + wm)*4 + mf))*64 + lane;
      ah[mf] = *(const s16x8*)&zhi[slot*8];
      al[mf] = *(const s16x8*)&zlo[slot*8];
    }
#pragma unroll
    for (int nf = 0; nf < 4; ++nf){
      size_t slot = ((size_t)((ntile*4 + kk)*8 + wn*4 + nf))*64 + lane;
      bh8[nf] = *(const s16x8*)&ehp[slot*8];
      bl8[nf] = *(const s16x8*)&elp[slot*8];
    }
#pragma unroll
    for (int mf = 0; mf < 4; ++mf)
#pragma unroll
      for (int nf = 0; nf < 4; ++nf){
        acc[mf][nf] = MFMA_B16(ah[mf], bh8[nf], acc[mf][nf]);
        acc[mf][nf] = MFMA_B16(ah[mf], bl8[nf], acc[mf][nf]);
        acc[mf][nf] = MFMA_B16(al[mf], bh8[nf], acc[mf][nf]);
      }
  }

#pragma unroll
  for (int p = 0; p < 2; ++p){
    __syncthreads();
    if (wm == p){
#pragma unroll
      for (int mf = 0; mf < 4; ++mf)
#pragma unroll
        for (int nf = 0; nf < 4; ++nf)
#pragma unroll
          for (int qq = 0; qq < 4; ++qq)
            fs[(mf*16 + lk*4 + qq)*136 + wn*64 + nf*16 + l15] = acc[mf][nf][qq];
    }
    __syncthreads();
#pragma unroll
    for (int it = 0; it < 8; ++it){
      int row = (t>>5) + it*8;             // 0..63
      int col = (t&31)*4;                  // 0..124
      f32x4 v = *(const f32x4*)&fs[row*136 + col];
      int gr = m0 + p*64 + row;
      if (gr < Bsz && n0 + col < NI)
        __builtin_nontemporal_store(v, (f32x4*)&out[(size_t)gr*NI + n0 + col]);
    }
  }
}

extern "C" void kernel_launch(void* const* d_in, const int* in_sizes, int n_in,
                              void* d_out, int out_size, void* d_ws, size_t ws_size,
                              hipStream_t stream){
  const int*   items    = (const int*)d_in[0];
  const int*   edge     = (const int*)d_in[1];
  const float* ew       = (const float*)d_in[2];
  const int*   item2idx = (const int*)d_in[3];
  const int*   bins     = (const int*)d_in[4];
  const int*   seg      = (const int*)d_in[5];
  const int*   pos      = (const int*)d_in[6];
  const float* item_emb = (const float*)d_in[8];
  const float* bin_emb  = (const float*)d_in[9];
  const float* Wih_f = (const float*)d_in[10];
  const float* Whh_f = (const float*)d_in[11];
  const float* bih_f = (const float*)d_in[12];
  const float* bhh_f = (const float*)d_in[13];
  const float* Wih_b = (const float*)d_in[14];
  const float* Whh_b = (const float*)d_in[15];
  const float* bih_b = (const float*)d_in[16];
  const float* bhh_b = (const float*)d_in[17];
  const float* w1    = (const float*)d_in[18];
  const float* w2    = (const float*)d_in[19];
  const float* v3    = (const float*)d_in[20];
  const float* Wih_s = (const float*)d_in[21];
  const float* Whh_s = (const float*)d_in[22];
  const float* bih_s = (const float*)d_in[23];
  const float* bhh_s = (const float*)d_in[24];
  const float* w3    = (const float*)d_in[25];
  const float* b3    = (const float*)d_in[26];
  float* out = (float*)d_out;

  const int NN = in_sizes[0];          // 25500 graph nodes
  const int NE = in_sizes[2];          // 51000 edges
  const int T  = in_sizes[3];          // 25500 tokens
  const int B  = in_sizes[7];          // 1000 sessions
  const int NI = in_sizes[8] / D;      // 100000 items

  const size_t NG  = (size_t)NN * D;   // 3,264,000
  const size_t BLD = (size_t)B * L * D;
  const int ntilesN = (NI + FBN - 1)/FBN;       // 782
  const int nslots  = ntilesN * 2048;           // packed B slots (8 shorts each)

  float* ws   = (float*)d_ws;
  float* accA = ws;                                   // NG
  float* xB   = ws + NG;                              // NG
  float* xC   = ws + 2*NG;                            // NG
  float* outf = ws + 3*NG;                            // BLD
  float* outb = outf + BLD;                           // BLD
  float* cpad = outb + BLD;                           // BLD
  int*   tokmap = (int*)(cpad + BLD);                 // B*L
  float* tabf = (float*)(tokmap + (size_t)B*L);       // 3840
  float* tabb = tabf + NBIN*G3;                       // 3840
  unsigned short* zhi = (unsigned short*)(tabb + NBIN*G3);    // 1024*128 shorts (packed A)
  unsigned short* zlo = zhi + 1024*128;               // 1024*128 shorts
  int* off    = (int*)(zlo + 1024*128);               // NN+1
  int* csrs   = off + NN + 1;                         // NE
  float* csrw = (float*)(csrs + NE);                  // NE
  unsigned short* ehp = (unsigned short*)(csrw + NE); // dedicated packed emb (~25.6MB)
  unsigned short* elp = ehp + (size_t)nslots*8;       // ~25.6MB
  float* xps  = (float*)(elp + (size_t)nslots*8);     // dedicated T*G3 (~39MB)

  // 1) prep: tables + h0 init + cpad zero + tokmap=-1 + packed-A zero
  hipLaunchKernelGGL(k_prep, dim3(2048), dim3(256), 0, stream,
                     bin_emb, Wih_f, bih_f, Wih_b, bih_b, item_emb, items,
                     tabf, tabb, accA, xB, cpad, tokmap, zhi, zlo,
                     (long long)NG, (long long)BLD, B*L);
  // 2) CSR build: count+scan+fill, single block (deg/cursor in LDS)
  hipLaunchKernelGGL(k_csr1, dim3(1), dim3(1024), 0, stream,
                     edge, edge+NE, ew, off, csrs, csrw, NN, NE);
  // 3) GCN: 3 gather layers (no atomics, fused accum)
  const int ggrid = (int)((NG + 255)/256);
  hipLaunchKernelGGL(k_gath, dim3(ggrid), dim3(256), 0, stream, xB, xC, accA, off, csrs, csrw, (int)NG);
  hipLaunchKernelGGL(k_gath, dim3(ggrid), dim3(256), 0, stream, xC, xB, accA, off, csrs, csrw, (int)NG);
  hipLaunchKernelGGL(k_gath, dim3(ggrid), dim3(256), 0, stream, xB, xC, accA, off, csrs, csrw, (int)NG);
  // 4) bidirectional GRU (fragment-local MFMA, dbuf h, split chains)
  hipLaunchKernelGGL(k_gru_fb, dim3((B+15)/16, 2), dim3(512), 0, stream,
                     Whh_f, Whh_b, bhh_f, bhh_b, tabf, tabb, bins, B, outf, outb);
  // 5) fused attn: e_hat/beta/c + xps (c consumed from registers)
  hipLaunchKernelGGL(k_attn, dim3(256), dim3(512), 0, stream,
                     outf, outb, accA, item2idx, w1, w2, v3, Wih_s, bih_s,
                     seg, pos, T, cpad, tokmap, xps);
  // 6) short GRU + final gate (zl from cpad) -> packed zhi/zlo; idle blocks pack item_emb
  {
    int nGru = (B + 15)/16;              // 63
    hipLaunchKernelGGL(k_grus, dim3(256), dim3(512), 0, stream,
                       Whh_s, bhh_s, bih_s, xps, tokmap, cpad, w3, b3, B, zhi, zlo,
                       item_emb, ehp, elp, NI, nslots, nGru);
  }
  // 7) out = z @ emb.T
  {
    int mtiles = (B + FBM - 1)/FBM;      // 8
    hipLaunchKernelGGL(k_fmm, dim3(mtiles*ntilesN), dim3(256), 0, stream,
                       zhi, zlo, ehp, elp, out, NI, B);
  }
}

// Round 14
// 445.928 us; speedup vs baseline: 1.2262x; 1.2262x over previous
//
#include <hip/hip_runtime.h>
#include <hip/hip_fp16.h>

// Problem constants (fixed by the harness' setup_inputs):
//   B=1000, L=50, D=128, NUM_ITEM=100000, NBIN=10, T=25500, n_edges=51000
#define D    128
#define L    50
#define G3   384          // 3*D
#define NBIN 10
#define NNMAX 25600       // graph nodes (25500) upper bound for LDS CSR build

// final-matmul tile params
#define FBM 128
#define FBN 128

typedef float f32x4 __attribute__((ext_vector_type(4)));
typedef short s16x8 __attribute__((ext_vector_type(8)));

#define MFMA_B16(a,b,c) __builtin_amdgcn_mfma_f32_16x16x32_bf16(a,b,c,0,0,0)

__device__ __forceinline__ float sigm(float x){ return 1.f/(1.f+__expf(-x)); }
__device__ __forceinline__ float tanh_fast(float x){
  float xx = fminf(fmaxf(x,-15.f),15.f);
  float e  = __expf(2.f*xx);
  return (e-1.f)/(e+1.f);
}

// split fp32 -> (hi bf16, lo bf16): x ~= hi + lo to ~2^-17 rel
#define SPLIT1(x, hu, lu) { unsigned u_ = __float_as_uint(x); hu = u_ >> 16; \
  float hf_ = __uint_as_float(u_ & 0xffff0000u); float lf_ = (x) - hf_; \
  lu = __float_as_uint(lf_) >> 16; }

__device__ __forceinline__ void split8(f32x4 a, f32x4 b, s16x8& hi, s16x8& lo){
  s16x8 h, l;
#pragma unroll
  for (int i=0;i<4;++i){
    unsigned hu, lu;
    SPLIT1(a[i], hu, lu)
    h[i] = (short)hu; l[i] = (short)lu;
  }
#pragma unroll
  for (int i=0;i<4;++i){
    unsigned hu, lu;
    SPLIT1(b[i], hu, lu)
    h[4+i] = (short)hu; l[4+i] = (short)lu;
  }
  hi = h; lo = l;
}

// ---------------- mega prep: tables + h0 init + zeros + tokmap + packed-A zero ----------------
__global__ void k_prep(const float* __restrict__ bin_emb,
                       const float* __restrict__ Wf, const float* __restrict__ bf,
                       const float* __restrict__ Wb, const float* __restrict__ bb,
                       const float* __restrict__ item_emb, const int* __restrict__ items,
                       float* __restrict__ tabf, float* __restrict__ tabb,
                       float* __restrict__ accA, float* __restrict__ xB,
                       float* __restrict__ cpad, int* __restrict__ tokmap,
                       unsigned short* __restrict__ zhi, unsigned short* __restrict__ zlo,
                       long long NG, long long BLD, int BL){
  const long long r1 = 7680, r2 = r1 + NG, r3 = r2 + BLD, r4 = r3 + BL;
  const long long ZP = 1024*128;           // packed A rows buffer (zero ALL; k_grus fills valid)
  const long long total = r4 + 2*ZP;
  for (long long i = (long long)blockIdx.x*256 + threadIdx.x; i < total;
       i += (long long)gridDim.x*256){
    if (i < r1){
      int id = (int)i; int dirr = id / (NBIN*G3); int rr = id % (NBIN*G3);
      int v = rr / G3, g = rr % G3;
      const float* W  = dirr ? Wb : Wf;
      const float* bi = dirr ? bb : bf;
      float a = bi[g];
      for (int d = 0; d < D; ++d) a += bin_emb[v*D+d]*W[g*D+d];
      (dirr ? tabb : tabf)[v*G3+g] = a;
    } else if (i < r2){
      long long k = i - r1;
      int nn = (int)(k>>7), d = (int)(k&127);
      float v = item_emb[(size_t)items[nn]*D + d];
      accA[k] = v; xB[k] = v;
    } else if (i < r3){
      cpad[i - r2] = 0.f;
    } else if (i < r4){
      tokmap[i - r3] = -1;
    } else {
      long long k = i - r4;
      if (k < ZP) zhi[k] = 0;
      else        zlo[k - ZP] = 0;
    }
  }
}

// ---------------- CSR: count + scan in ONE single-block kernel (deg in LDS) ----------------
__global__ __launch_bounds__(1024) void k_csr1(const int* __restrict__ dst,
                                               int* __restrict__ off, int* __restrict__ cursor,
                                               int nn, int ne){
  __shared__ int degs[NNMAX];    // 102 KB
  __shared__ int part[1024];     // 4 KB
  int tid = threadIdx.x;
  for (int i = tid; i < nn; i += 1024) degs[i] = 0;
  __syncthreads();
  for (int e = tid; e < ne; e += 1024) atomicAdd(&degs[dst[e]], 1);
  __syncthreads();
  int chunk = (nn + 1023) >> 10;
  int c0 = tid*chunk;
  int s = 0;
  for (int k = 0; k < chunk; ++k){ int v = c0+k; if (v < nn) s += degs[v]; }
  part[tid] = s; __syncthreads();
  for (int d = 1; d < 1024; d <<= 1){
    int v = (tid >= d) ? part[tid-d] : 0;
    __syncthreads();
    part[tid] += v;
    __syncthreads();
  }
  int run = part[tid] - s;       // exclusive base
  for (int k = 0; k < chunk; ++k){
    int v = c0+k;
    if (v < nn){ off[v] = run; cursor[v] = run; run += degs[v]; }
  }
  if (tid == 1023) off[nn] = part[1023];
}
__global__ void k_fill(const int* __restrict__ src, const int* __restrict__ dst,
                       const float* __restrict__ ew, int* __restrict__ cursor,
                       int* __restrict__ csrs, float* __restrict__ csrw, int ne){
  int e = blockIdx.x*256 + threadIdx.x;
  if (e >= ne) return;
  int p = atomicAdd(&cursor[dst[e]], 1);
  csrs[p] = src[e];
  csrw[p] = ew[e];
}
// gather-based propagation layer: xn[v] = sum_in x[src]*w; acc += xn
__global__ void k_gath(const float* __restrict__ x, float* __restrict__ xn,
                       float* __restrict__ acc,
                       const int* __restrict__ off, const int* __restrict__ csrs,
                       const float* __restrict__ csrw, int n){
  int i = blockIdx.x*256 + threadIdx.x;
  if (i >= n) return;
  int v = i >> 7, d = i & (D-1);
  int a = off[v], b = off[v+1];
  float s = 0.f;
  for (int k = a; k < b; ++k)
    s += x[(size_t)csrs[k]*D + d] * csrw[k];
  xn[i] = s;
  acc[i] += s;
}

// ============ MFMA GRU: double-buffered h (1 barrier/step), 2-way split chains ============
__global__ __launch_bounds__(512) void k_gru_fb(
    const float* __restrict__ Whh_f, const float* __restrict__ Whh_b,
    const float* __restrict__ bhh_f, const float* __restrict__ bhh_b,
    const float* __restrict__ tabf,  const float* __restrict__ tabb,
    const int*   __restrict__ bins,  int Bn,
    float* __restrict__ outf, float* __restrict__ outbrev){
  const int dir = blockIdx.y;
  const int b0  = blockIdx.x * 16;
  const float* Whh = dir ? Whh_b : Whh_f;
  const float* bhh = dir ? bhh_b : bhh_f;
  const float* tab = dir ? tabb  : tabf;
  float* outp = dir ? outbrev : outf;

  __shared__ unsigned short hhi[2*16*128];   // 8 KB double-buffered, swizzled [sess][j]
  __shared__ unsigned short hlo[2*16*128];   // 8 KB
  __shared__ float xts[NBIN*G3];             // 15 KB
  __shared__ int   binr[16][L];

  const int tid = threadIdx.x;
  const int wv = tid>>6, lane = tid&63;
  const int l15 = lane&15, lk = lane>>4;
  const int jb = wv*16;
  const int jq = jb + lk*4;               // first of this thread's 4 j's

  s16x8 whi[3][4], wlo[3][4];
#pragma unroll
  for (int g3i = 0; g3i < 3; ++g3i)
#pragma unroll
    for (int ks = 0; ks < 4; ++ks){
      const f32x4* s = (const f32x4*)&Whh[(size_t)(g3i*D + jb + l15)*D + ks*32 + lk*8];
      split8(s[0], s[1], whi[g3i][ks], wlo[g3i][ks]);
    }
  f32x4 bhv[3];
#pragma unroll
  for (int g3i = 0; g3i < 3; ++g3i) bhv[g3i] = *(const f32x4*)&bhh[g3i*D + jq];

  for (int i = tid; i < NBIN*G3; i += 512) xts[i] = tab[i];
  for (int i = tid; i < 16*L; i += 512){
    int r = i / L, t = i % L;
    binr[r][t] = (b0 + r < Bn) ? bins[(b0+r)*L + (dir ? (L-1-t) : t)] : 0;
  }
  for (int i = tid; i < 2*16*128; i += 512){ hhi[i] = 0; hlo[i] = 0; }

  const int sess = l15;
  const bool sv = (b0 + sess) < Bn;
  float hreg[4] = {0.f,0.f,0.f,0.f};
  const int wbyte = sess*256 + (((jq>>3) ^ (sess&7))<<4) + ((jq&7)<<1);
  int cur = 0;
  __syncthreads();

  for (int t = 0; t < L; ++t){
    // ---- matmul: gh = Whh_perm @ (h_hi + h_lo); 6 split accumulator chains
    f32x4 c0a={0.f,0.f,0.f,0.f}, c1a=c0a, c2a=c0a, c0b=c0a, c1b=c0a, c2b=c0a;
    const int rb = cur*4096;
#pragma unroll
    for (int ks = 0; ks < 2; ++ks){
      int off = rb + l15*256 + ((((ks<<2)+lk) ^ (l15&7)) << 4);
      s16x8 bh8 = *(const s16x8*)((const char*)hhi + off);
      s16x8 bl8 = *(const s16x8*)((const char*)hlo + off);
      c0a = MFMA_B16(whi[0][ks], bh8, c0a); c0a = MFMA_B16(whi[0][ks], bl8, c0a); c0a = MFMA_B16(wlo[0][ks], bh8, c0a);
      c1a = MFMA_B16(whi[1][ks], bh8, c1a); c1a = MFMA_B16(whi[1][ks], bl8, c1a); c1a = MFMA_B16(wlo[1][ks], bh8, c1a);
      c2a = MFMA_B16(whi[2][ks], bh8, c2a); c2a = MFMA_B16(whi[2][ks], bl8, c2a); c2a = MFMA_B16(wlo[2][ks], bh8, c2a);
    }
#pragma unroll
    for (int ks = 2; ks < 4; ++ks){
      int off = rb + l15*256 + ((((ks<<2)+lk) ^ (l15&7)) << 4);
      s16x8 bh8 = *(const s16x8*)((const char*)hhi + off);
      s16x8 bl8 = *(const s16x8*)((const char*)hlo + off);
      c0b = MFMA_B16(whi[0][ks], bh8, c0b); c0b = MFMA_B16(whi[0][ks], bl8, c0b); c0b = MFMA_B16(wlo[0][ks], bh8, c0b);
      c1b = MFMA_B16(whi[1][ks], bh8, c1b); c1b = MFMA_B16(whi[1][ks], bl8, c1b); c1b = MFMA_B16(wlo[1][ks], bh8, c1b);
      c2b = MFMA_B16(whi[2][ks], bh8, c2b); c2b = MFMA_B16(whi[2][ks], bl8, c2b); c2b = MFMA_B16(wlo[2][ks], bh8, c2b);
    }
    f32x4 c0 = c0a + c0b, c1 = c1a + c1b, c2 = c2a + c2b;
    // ---- elementwise (registers); write h to OTHER buffer -> no pre-barrier needed
    int bin = binr[sess][t];
    const float* xb = &xts[bin*G3];
    f32x4 xr4 = *(const f32x4*)&xb[jq];
    f32x4 xz4 = *(const f32x4*)&xb[D + jq];
    f32x4 xn4 = *(const f32x4*)&xb[2*D + jq];
    ushort4 hi4, lo4;
    f32x4 hn4;
#pragma unroll
    for (int qq = 0; qq < 4; ++qq){
      float gr = c0[qq] + bhv[0][qq];
      float gz = c1[qq] + bhv[1][qq];
      float gn = c2[qq] + bhv[2][qq];
      float rr = sigm(xr4[qq] + gr);
      float zz = sigm(xz4[qq] + gz);
      float nn = tanh_fast(xn4[qq] + rr*gn);
      float hnew = (1.f-zz)*nn + zz*hreg[qq];
      hreg[qq] = hnew;
      unsigned hu, lu; SPLIT1(hnew, hu, lu)
      ((unsigned short*)&hi4)[qq] = (unsigned short)hu;
      ((unsigned short*)&lo4)[qq] = (unsigned short)lu;
      hn4[qq] = hnew;
    }
    int wb = (cur^1)*4096 + wbyte;
    *(ushort4*)((char*)hhi + wb) = hi4;
    *(ushort4*)((char*)hlo + wb) = lo4;
    if (sv){
      float4 o = make_float4(hn4[0],hn4[1],hn4[2],hn4[3]);
      *(float4*)&outp[((size_t)(b0+sess)*L + (dir ? (L-1-t) : t))*D + jq] = o;
    }
    __syncthreads();
    cur ^= 1;
  }
}

// ---------------- e_hat + beta + c, MFMA version (split chains) ----------------
__global__ __launch_bounds__(512) void k_beta2(
    const float* __restrict__ outf, const float* __restrict__ outbrev,
    const float* __restrict__ accA, const int* __restrict__ idxmap,
    const float* __restrict__ w1, const float* __restrict__ w2,
    const float* __restrict__ v3,
    const int* __restrict__ seg, const int* __restrict__ pos, int T,
    float* __restrict__ c_pad, int* __restrict__ tokmap){
  __shared__ unsigned short Bhi[32*256];   // 16 KB  [tok][K=256], swizzled 16B slots
  __shared__ unsigned short Blo[32*256];   // 16 KB
  __shared__ float w1s[2*D];
  __shared__ float betas[32];

  const int tid = threadIdx.x;
  const int wv = tid>>6, lane = tid&63;
  const int l15 = lane&15, lk = lane>>4;

  // loop-invariant w2 fragments: wave wv owns u-cols [16wv,16wv+16), K=256 -> 8 ks
  s16x8 w2hi[8], w2lo[8];
#pragma unroll
  for (int ks = 0; ks < 8; ++ks){
    const f32x4* s = (const f32x4*)&w2[(size_t)(wv*16 + l15)*256 + ks*32 + lk*8];
    split8(s[0], s[1], w2hi[ks], w2lo[ks]);
  }
  f32x4 v3q = *(const f32x4*)&v3[wv*16 + lk*4];
  for (int i = tid; i < 2*D; i += 512) w1s[i] = w1[i];
  __syncthreads();

  const int tok = tid >> 4;            // 0..31
  const int d0  = (tid & 15) * 8;      // this thread's 8 dims
  const int sw  = (tid & 15) ^ (tok & 7);   // swizzled 16B slot for hf
  const int ntiles = (T + 31) >> 5;

  for (int tile = blockIdx.x; tile < ntiles; tile += gridDim.x){
    int t = tile*32 + tok;
    bool valid = (t < T);
    // ---- phase 1: gather, gate, e_hat, stage B
    int sp = 0;
    f32x4 ef0 = {0,0,0,0}, ef1 = ef0, eb0 = ef0, eb1 = ef0, hf0 = ef0, hf1 = ef0;
    if (valid){
      sp = seg[t]*L + pos[t];
      const f32x4* pf = (const f32x4*)&outf[(size_t)sp*D + d0];
      const f32x4* pb = (const f32x4*)&outbrev[(size_t)sp*D + d0];
      const f32x4* ph = (const f32x4*)&accA[(size_t)idxmap[t]*D + d0];
      ef0 = pf[0]; ef1 = pf[1];
      eb0 = pb[0]; eb1 = pb[1];
      hf0 = ph[0]; hf1 = ph[1];
#pragma unroll
      for (int k=0;k<4;++k){ hf0[k]*=0.25f; hf1[k]*=0.25f; }
    }
    float p = 0.f;
#pragma unroll
    for (int k=0;k<4;++k){
      p += ef0[k]*w1s[d0+k]     + eb0[k]*w1s[D+d0+k];
      p += ef1[k]*w1s[d0+4+k]   + eb1[k]*w1s[D+d0+4+k];
    }
    p += __shfl_xor(p,1); p += __shfl_xor(p,2);
    p += __shfl_xor(p,4); p += __shfl_xor(p,8);
    float gate = sigm(p);
    f32x4 eh0, eh1;
#pragma unroll
    for (int k=0;k<4;++k){
      eh0[k] = gate*ef0[k] + (1.f-gate)*eb0[k];
      eh1[k] = gate*ef1[k] + (1.f-gate)*eb1[k];
    }
    {
      s16x8 h8, l8;
      split8(hf0, hf1, h8, l8);
      int byte = tok*512 + (sw<<4);
      *(s16x8*)((char*)Bhi + byte) = h8;
      *(s16x8*)((char*)Blo + byte) = l8;
      split8(eh0, eh1, h8, l8);
      byte = tok*512 + ((16+((tid&15)^(tok&7)))<<4);
      *(s16x8*)((char*)Bhi + byte) = h8;
      *(s16x8*)((char*)Blo + byte) = l8;
    }
    if (tid < 32) betas[tid] = 0.f;
    __syncthreads();
    // ---- phase 2: u = w2 @ B (two 16-token subtiles), tanh, v3 reduce
#pragma unroll
    for (int tt = 0; tt < 2; ++tt){
      f32x4 ca = {0.f,0.f,0.f,0.f}, cb = ca;
#pragma unroll
      for (int ks = 0; ks < 4; ++ks){
        int s_ = ((ks<<2)+lk);
        int off = (tt*16 + l15)*512 + ((s_ ^ (l15&7)) << 4);
        s16x8 bh8 = *(const s16x8*)((const char*)Bhi + off);
        s16x8 bl8 = *(const s16x8*)((const char*)Blo + off);
        ca = MFMA_B16(w2hi[ks], bh8, ca);
        ca = MFMA_B16(w2hi[ks], bl8, ca);
        ca = MFMA_B16(w2lo[ks], bh8, ca);
      }
#pragma unroll
      for (int ks = 4; ks < 8; ++ks){
        int s_ = ((ks<<2)+lk);
        int off = (tt*16 + l15)*512 + ((s_ ^ (l15&7)) << 4);
        s16x8 bh8 = *(const s16x8*)((const char*)Bhi + off);
        s16x8 bl8 = *(const s16x8*)((const char*)Blo + off);
        cb = MFMA_B16(w2hi[ks], bh8, cb);
        cb = MFMA_B16(w2hi[ks], bl8, cb);
        cb = MFMA_B16(w2lo[ks], bh8, cb);
      }
      f32x4 c = ca + cb;
      float pv = 0.f;
#pragma unroll
      for (int qq = 0; qq < 4; ++qq) pv += tanh_fast(c[qq]) * v3q[qq];
      pv += __shfl_xor(pv, 16);
      pv += __shfl_xor(pv, 32);
      if (lk == 0) atomicAdd(&betas[tt*16 + l15], pv);
    }
    __syncthreads();
    // ---- phase 3: c = beta*hf, write out
    if (valid){
      float beta = betas[tok];
      f32x4 c0, c1;
#pragma unroll
      for (int k=0;k<4;++k){ c0[k] = beta*hf0[k]; c1[k] = beta*hf1[k]; }
      f32x4* pc = (f32x4*)&c_pad[(size_t)sp*D + d0];
      pc[0] = c0; pc[1] = c1;
      if ((tid & 15) == 0) tokmap[sp] = t;
    }
    __syncthreads();   // betas/B reuse protection
  }
}

// ---------------- xps = c @ Wih_s.T + bih_s (MFMA) + fused z_long prologue ----------------
__global__ __launch_bounds__(512) void k_xps2(
    const float* __restrict__ c_pad, const int* __restrict__ seg,
    const int* __restrict__ pos, const float* __restrict__ Wih,
    const float* __restrict__ bih, int T, float* __restrict__ xps,
    float* __restrict__ zl, int Bn){
  __shared__ unsigned short Bhi[32*128];   // 8 KB [tok][K=128]
  __shared__ unsigned short Blo[32*128];   // 8 KB
  __shared__ float us[32*388];             // 48.5 KB (388 = 4 mod 32 -> 2-way)
  __shared__ float bihs[G3];

  const int tid = threadIdx.x;
  const int wv = tid>>6, lane = tid&63;
  const int l15 = lane&15, lk = lane>>4;
  const int gbase = wv * 48;

  // fused z_long: zl[b][j] = sum_l c_pad[(b*L+l)*D + j]
  for (int i = blockIdx.x*512 + tid; i < Bn*D; i += gridDim.x*512){
    int b = i >> 7, j = i & (D-1);
    float s = 0.f;
    for (int l = 0; l < L; ++l) s += c_pad[((size_t)b*L + l)*D + j];
    zl[i] = s;
  }

  s16x8 whi[3][4], wlo[3][4];
#pragma unroll
  for (int mt = 0; mt < 3; ++mt)
#pragma unroll
    for (int ks = 0; ks < 4; ++ks){
      const f32x4* s = (const f32x4*)&Wih[(size_t)(gbase + mt*16 + l15)*D + ks*32 + lk*8];
      split8(s[0], s[1], whi[mt][ks], wlo[mt][ks]);
    }
  for (int i = tid; i < G3; i += 512) bihs[i] = bih[i];
  __syncthreads();

  const int tok = tid >> 4;
  const int d0  = (tid & 15) * 8;
  const int ntiles = (T + 31) >> 5;

  for (int tile = blockIdx.x; tile < ntiles; tile += gridDim.x){
    int t = tile*32 + tok;
    bool valid = (t < T);
    // ---- phase 1: stage c tokens
    f32x4 x0 = {0,0,0,0}, x1 = x0;
    if (valid){
      int sp = seg[t]*L + pos[t];
      const f32x4* pc = (const f32x4*)&c_pad[(size_t)sp*D + d0];
      x0 = pc[0]; x1 = pc[1];
    }
    {
      s16x8 h8, l8;
      split8(x0, x1, h8, l8);
      int byte = tok*256 + ((((tid&15)) ^ (tok&7))<<4);
      *(s16x8*)((char*)Bhi + byte) = h8;
      *(s16x8*)((char*)Blo + byte) = l8;
    }
    __syncthreads();
    // ---- phase 2: MFMA (split chains) + stage u in LDS
#pragma unroll
    for (int tt = 0; tt < 2; ++tt){
      f32x4 ca[3], cb[3];
#pragma unroll
      for (int mt = 0; mt < 3; ++mt){ f32x4 z = {0,0,0,0}; ca[mt] = z; cb[mt] = z; }
#pragma unroll
      for (int ks = 0; ks < 2; ++ks){
        int off = (tt*16 + l15)*256 + ((((ks<<2)+lk) ^ (l15&7)) << 4);
        s16x8 bh8 = *(const s16x8*)((const char*)Bhi + off);
        s16x8 bl8 = *(const s16x8*)((const char*)Blo + off);
        ca[0] = MFMA_B16(whi[0][ks], bh8, ca[0]); ca[0] = MFMA_B16(whi[0][ks], bl8, ca[0]); ca[0] = MFMA_B16(wlo[0][ks], bh8, ca[0]);
        ca[1] = MFMA_B16(whi[1][ks], bh8, ca[1]); ca[1] = MFMA_B16(whi[1][ks], bl8, ca[1]); ca[1] = MFMA_B16(wlo[1][ks], bh8, ca[1]);
        ca[2] = MFMA_B16(whi[2][ks], bh8, ca[2]); ca[2] = MFMA_B16(whi[2][ks], bl8, ca[2]); ca[2] = MFMA_B16(wlo[2][ks], bh8, ca[2]);
      }
#pragma unroll
      for (int ks = 2; ks < 4; ++ks){
        int off = (tt*16 + l15)*256 + ((((ks<<2)+lk) ^ (l15&7)) << 4);
        s16x8 bh8 = *(const s16x8*)((const char*)Bhi + off);
        s16x8 bl8 = *(const s16x8*)((const char*)Blo + off);
        cb[0] = MFMA_B16(whi[0][ks], bh8, cb[0]); cb[0] = MFMA_B16(whi[0][ks], bl8, cb[0]); cb[0] = MFMA_B16(wlo[0][ks], bh8, cb[0]);
        cb[1] = MFMA_B16(whi[1][ks], bh8, cb[1]); cb[1] = MFMA_B16(whi[1][ks], bl8, cb[1]); cb[1] = MFMA_B16(wlo[1][ks], bh8, cb[1]);
        cb[2] = MFMA_B16(whi[2][ks], bh8, cb[2]); cb[2] = MFMA_B16(whi[2][ks], bl8, cb[2]); cb[2] = MFMA_B16(wlo[2][ks], bh8, cb[2]);
      }
#pragma unroll
      for (int mt = 0; mt < 3; ++mt){
        f32x4 c = ca[mt] + cb[mt];
        *(f32x4*)&us[(tt*16 + l15)*388 + gbase + mt*16 + lk*4] = c;
      }
    }
    __syncthreads();
    // ---- phase 3: coalesced global write (+bias)
    for (int i4 = tid; i4 < 32*96; i4 += 512){
      int tk = i4 / 96, g4 = (i4 % 96) * 4;
      int tt2 = tile*32 + tk;
      if (tt2 < T){
        f32x4 u4 = *(const f32x4*)&us[tk*388 + g4];
        f32x4 b4 = *(const f32x4*)&bihs[g4];
#pragma unroll
        for (int k=0;k<4;++k) u4[k] += b4[k];
        *(f32x4*)&xps[(size_t)tt2*G3 + g4] = u4;
      }
    }
    __syncthreads();
  }
}

// ---------------- short GRU (dbuf h, split chains) + final gate -> packed z;
//                  idle blocks (>= nGru) run the emb fragment-pack (esplit) ----------------
__global__ __launch_bounds__(512) void k_grus(
    const float* __restrict__ Whh, const float* __restrict__ bhh,
    const float* __restrict__ bih,
    const float* __restrict__ xps, const int* __restrict__ tokmap,
    const float* __restrict__ zl, const float* __restrict__ w3,
    const float* __restrict__ b3, int Bn,
    unsigned short* __restrict__ zhi, unsigned short* __restrict__ zlo,
    const float* __restrict__ emb,
    unsigned short* __restrict__ ehp, unsigned short* __restrict__ elp,
    int NI, int nslots, int nGru){
  if (blockIdx.x >= nGru){
    // ---- esplit role: fragment-major pack of item_emb
    int nb = gridDim.x - nGru;
    for (int s = (blockIdx.x - nGru)*512 + threadIdx.x; s < nslots; s += nb*512){
      int lane = s & 63;
      int nfw  = (s>>6) & 7;
      int kk   = (s>>9) & 3;
      int ntl  = s >> 11;
      int row  = ntl*128 + (nfw>>2)*64 + (nfw&3)*16 + (lane&15);
      int d0   = kk*32 + (lane>>4)*8;
      s16x8 h8 = {0,0,0,0,0,0,0,0}, l8 = h8;
      if (row < NI){
        const f32x4* src = (const f32x4*)&emb[(size_t)row*D + d0];
        split8(src[0], src[1], h8, l8);
      }
      *(s16x8*)&ehp[(size_t)s*8] = h8;
      *(s16x8*)&elp[(size_t)s*8] = l8;
    }
    return;
  }
  const int b0 = blockIdx.x * 16;

  __shared__ unsigned short hhi[2*16*128];
  __shared__ unsigned short hlo[2*16*128];
  __shared__ int   maprow[16][L];
  __shared__ float redg[16];

  const int tid = threadIdx.x;
  const int wv = tid>>6, lane = tid&63;
  const int l15 = lane&15, lk = lane>>4;
  const int jb = wv*16;
  const int jq = jb + lk*4;

  s16x8 whi[3][4], wlo[3][4];
#pragma unroll
  for (int g3i = 0; g3i < 3; ++g3i)
#pragma unroll
    for (int ks = 0; ks < 4; ++ks){
      const f32x4* s = (const f32x4*)&Whh[(size_t)(g3i*D + jb + l15)*D + ks*32 + lk*8];
      split8(s[0], s[1], whi[g3i][ks], wlo[g3i][ks]);
    }
  f32x4 bhv[3], biv[3];
#pragma unroll
  for (int g3i = 0; g3i < 3; ++g3i){
    bhv[g3i] = *(const f32x4*)&bhh[g3i*D + jq];
    biv[g3i] = *(const f32x4*)&bih[g3i*D + jq];
  }
  for (int i = tid; i < 16*L; i += 512){
    int r = i / L, t = i % L;
    maprow[r][t] = (b0 + r < Bn) ? tokmap[(b0+r)*L + t] : -1;
  }
  for (int i = tid; i < 2*16*128; i += 512){ hhi[i] = 0; hlo[i] = 0; }

  const int sess = l15;
  const bool sv = (b0 + sess) < Bn;
  float hreg[4] = {0.f,0.f,0.f,0.f};
  const int wbyte = sess*256 + (((jq>>3) ^ (sess&7))<<4) + ((jq&7)<<1);
  int cur = 0;
  __syncthreads();

  for (int t = 0; t < L; ++t){
    int tok = maprow[sess][t];
    f32x4 xr4, xz4, xn4;
    if (tok >= 0){
      const float* xb = &xps[(size_t)tok*G3];
      xr4 = *(const f32x4*)&xb[jq];
      xz4 = *(const f32x4*)&xb[D + jq];
      xn4 = *(const f32x4*)&xb[2*D + jq];
    } else { xr4 = biv[0]; xz4 = biv[1]; xn4 = biv[2]; }
    f32x4 c0a={0.f,0.f,0.f,0.f}, c1a=c0a, c2a=c0a, c0b=c0a, c1b=c0a, c2b=c0a;
    const int rb = cur*4096;
#pragma unroll
    for (int ks = 0; ks < 2; ++ks){
      int off = rb + l15*256 + ((((ks<<2)+lk) ^ (l15&7)) << 4);
      s16x8 bh8 = *(const s16x8*)((const char*)hhi + off);
      s16x8 bl8 = *(const s16x8*)((const char*)hlo + off);
      c0a = MFMA_B16(whi[0][ks], bh8, c0a); c0a = MFMA_B16(whi[0][ks], bl8, c0a); c0a = MFMA_B16(wlo[0][ks], bh8, c0a);
      c1a = MFMA_B16(whi[1][ks], bh8, c1a); c1a = MFMA_B16(whi[1][ks], bl8, c1a); c1a = MFMA_B16(wlo[1][ks], bh8, c1a);
      c2a = MFMA_B16(whi[2][ks], bh8, c2a); c2a = MFMA_B16(whi[2][ks], bl8, c2a); c2a = MFMA_B16(wlo[2][ks], bh8, c2a);
    }
#pragma unroll
    for (int ks = 2; ks < 4; ++ks){
      int off = rb + l15*256 + ((((ks<<2)+lk) ^ (l15&7)) << 4);
      s16x8 bh8 = *(const s16x8*)((const char*)hhi + off);
      s16x8 bl8 = *(const s16x8*)((const char*)hlo + off);
      c0b = MFMA_B16(whi[0][ks], bh8, c0b); c0b = MFMA_B16(whi[0][ks], bl8, c0b); c0b = MFMA_B16(wlo[0][ks], bh8, c0b);
      c1b = MFMA_B16(whi[1][ks], bh8, c1b); c1b = MFMA_B16(whi[1][ks], bl8, c1b); c1b = MFMA_B16(wlo[1][ks], bh8, c1b);
      c2b = MFMA_B16(whi[2][ks], bh8, c2b); c2b = MFMA_B16(whi[2][ks], bl8, c2b); c2b = MFMA_B16(wlo[2][ks], bh8, c2b);
    }
    f32x4 c0 = c0a + c0b, c1 = c1a + c1b, c2 = c2a + c2b;
    ushort4 hi4, lo4;
#pragma unroll
    for (int qq = 0; qq < 4; ++qq){
      float gr = c0[qq] + bhv[0][qq];
      float gz = c1[qq] + bhv[1][qq];
      float gn = c2[qq] + bhv[2][qq];
      float rr = sigm(xr4[qq] + gr);
      float zz = sigm(xz4[qq] + gz);
      float nn = tanh_fast(xn4[qq] + rr*gn);
      float hnew = (1.f-zz)*nn + zz*hreg[qq];
      hreg[qq] = hnew;
      unsigned hu, lu; SPLIT1(hnew, hu, lu)
      ((unsigned short*)&hi4)[qq] = (unsigned short)hu;
      ((unsigned short*)&lo4)[qq] = (unsigned short)lu;
    }
    int wb = (cur^1)*4096 + wbyte;
    *(ushort4*)((char*)hhi + wb) = hi4;
    *(ushort4*)((char*)hlo + wb) = lo4;
    __syncthreads();
    cur ^= 1;
  }

  // ---- fused final gate: z = f*zl + (1-f)*h_final, stored PACKED (fragment-major)
  if (tid < 16) redg[tid] = 0.f;
  __syncthreads();
  f32x4 zl4 = {0.f,0.f,0.f,0.f};
  if (sv) zl4 = *(const f32x4*)&zl[(size_t)(b0+sess)*D + jq];
  f32x4 w34 = *(const f32x4*)&w3[jq];
  float part = 0.f;
#pragma unroll
  for (int qq = 0; qq < 4; ++qq) part += (zl4[qq] + hreg[qq]) * w34[qq];
  if (sv) atomicAdd(&redg[sess], part);
  __syncthreads();
  if (sv){
    float f = sigm(redg[sess] + b3[0]);
    ushort4 h4, l4;
#pragma unroll
    for (int qq = 0; qq < 4; ++qq){
      float zv = f*zl4[qq] + (1.f-f)*hreg[qq];
      unsigned hu, lu; SPLIT1(zv, hu, lu)
      ((unsigned short*)&h4)[qq] = (unsigned short)hu;
      ((unsigned short*)&l4)[qq] = (unsigned short)lu;
    }
    int row = b0 + sess;
    int mtile = row >> 7, r128 = row & 127;
    int wmr = r128 >> 6, mfr = (r128 >> 4) & 3, l15r = r128 & 15;
    int kkr = jq >> 5, lkr = (jq & 31) >> 3, e0 = jq & 7;
    int laner = lkr*16 + l15r;
    size_t slot = ((size_t)(((mtile*4 + kkr)*2 + wmr)*4 + mfr))*64 + laner;
    *(ushort4*)&zhi[slot*8 + e0] = h4;
    *(ushort4*)&zlo[slot*8 + e0] = l4;
  }
}

// ---------------- out = z @ emb.T  (fragment-major packed operands: 1KB contiguous loads) ----------------
__global__ __launch_bounds__(256, 3) void k_fmm(
    const unsigned short* __restrict__ zhi, const unsigned short* __restrict__ zlo,
    const unsigned short* __restrict__ ehp, const unsigned short* __restrict__ elp,
    float* __restrict__ out, int NI, int Bsz){
  __shared__ float fs[64*136];   // 34 KB epilogue staging

  int nwg = gridDim.x;
  int hw  = blockIdx.x;
  int q8 = nwg >> 3, r8 = nwg & 7;
  int xcd = hw & 7, idx = hw >> 3;
  int logical = (xcd < r8 ? xcd*(q8+1) : r8*(q8+1) + (xcd-r8)*q8) + idx;
  int ntile = logical >> 3;       // 8 consecutive logicals share an emb tile
  int mtile = logical & 7;
  int m0 = mtile*FBM;
  int n0 = ntile*FBN;

  const int t    = threadIdx.x;
  const int lane = t & 63;
  const int wid  = t >> 6;
  const int wm   = wid >> 1, wn = wid & 1;   // 2x2 wave grid, 64x64 each
  const int l15  = lane & 15, lk = lane >> 4;

  f32x4 acc[4][4];
#pragma unroll
  for (int i = 0; i < 4; ++i)
#pragma unroll
    for (int jj = 0; jj < 4; ++jj){ f32x4 z4 = {0.f,0.f,0.f,0.f}; acc[i][jj] = z4; }

  // 4 k-steps of 32; all loads are 64-lane-contiguous (1KB per instruction)
#pragma unroll
  for (int kk = 0; kk < 4; ++kk){
    s16x8 ah[4], al[4], bh8[4], bl8[4];
#pragma unroll
    for (int mf = 0; mf < 4; ++mf){
      size_t slot = ((size_t)(((mtile*4 + kk)*2 + wm)*4 + mf))*64 + lane;
      ah[mf] = *(const s16x8*)&zhi[slot*8];
      al[mf] = *(const s16x8*)&zlo[slot*8];
    }
#pragma unroll
    for (int nf = 0; nf < 4; ++nf){
      size_t slot = ((size_t)((ntile*4 + kk)*8 + wn*4 + nf))*64 + lane;
      bh8[nf] = *(const s16x8*)&ehp[slot*8];
      bl8[nf] = *(const s16x8*)&elp[slot*8];
    }
#pragma unroll
    for (int mf = 0; mf < 4; ++mf)
#pragma unroll
      for (int nf = 0; nf < 4; ++nf){
        acc[mf][nf] = MFMA_B16(ah[mf], bh8[nf], acc[mf][nf]);
        acc[mf][nf] = MFMA_B16(ah[mf], bl8[nf], acc[mf][nf]);
        acc[mf][nf] = MFMA_B16(al[mf], bh8[nf], acc[mf][nf]);
      }
  }

  // ---- epilogue: 2 passes x 64 rows through LDS, nt coalesced stores
#pragma unroll
  for (int p = 0; p < 2; ++p){
    __syncthreads();
    if (wm == p){
#pragma unroll
      for (int mf = 0; mf < 4; ++mf)
#pragma unroll
        for (int nf = 0; nf < 4; ++nf)
#pragma unroll
          for (int qq = 0; qq < 4; ++qq)
            fs[(mf*16 + lk*4 + qq)*136 + wn*64 + nf*16 + l15] = acc[mf][nf][qq];
    }
    __syncthreads();
#pragma unroll
    for (int it = 0; it < 8; ++it){
      int row = (t>>5) + it*8;             // 0..63
      int col = (t&31)*4;                  // 0..124
      f32x4 v = *(const f32x4*)&fs[row*136 + col];
      int gr = m0 + p*64 + row;
      if (gr < Bsz && n0 + col < NI)
        __builtin_nontemporal_store(v, (f32x4*)&out[(size_t)gr*NI + n0 + col]);
    }
  }
}

extern "C" void kernel_launch(void* const* d_in, const int* in_sizes, int n_in,
                              void* d_out, int out_size, void* d_ws, size_t ws_size,
                              hipStream_t stream){
  const int*   items    = (const int*)d_in[0];
  const int*   edge     = (const int*)d_in[1];
  const float* ew       = (const float*)d_in[2];
  const int*   item2idx = (const int*)d_in[3];
  const int*   bins     = (const int*)d_in[4];
  const int*   seg      = (const int*)d_in[5];
  const int*   pos      = (const int*)d_in[6];
  const float* item_emb = (const float*)d_in[8];
  const float* bin_emb  = (const float*)d_in[9];
  const float* Wih_f = (const float*)d_in[10];
  const float* Whh_f = (const float*)d_in[11];
  const float* bih_f = (const float*)d_in[12];
  const float* bhh_f = (const float*)d_in[13];
  const float* Wih_b = (const float*)d_in[14];
  const float* Whh_b = (const float*)d_in[15];
  const float* bih_b = (const float*)d_in[16];
  const float* bhh_b = (const float*)d_in[17];
  const float* w1    = (const float*)d_in[18];
  const float* w2    = (const float*)d_in[19];
  const float* v3    = (const float*)d_in[20];
  const float* Wih_s = (const float*)d_in[21];
  const float* Whh_s = (const float*)d_in[22];
  const float* bih_s = (const float*)d_in[23];
  const float* bhh_s = (const float*)d_in[24];
  const float* w3    = (const float*)d_in[25];
  const float* b3    = (const float*)d_in[26];
  float* out = (float*)d_out;

  const int NN = in_sizes[0];          // 25500 graph nodes
  const int NE = in_sizes[2];          // 51000 edges
  const int T  = in_sizes[3];          // 25500 tokens
  const int B  = in_sizes[7];          // 1000 sessions
  const int NI = in_sizes[8] / D;      // 100000 items

  const size_t NG  = (size_t)NN * D;   // 3,264,000
  const size_t BLD = (size_t)B * L * D;
  const int ntilesN = (NI + FBN - 1)/FBN;       // 782
  const int nslots  = ntilesN * 2048;           // packed B slots (8 shorts each)

  float* ws   = (float*)d_ws;
  float* accA = ws;                                   // NG
  float* xB   = ws + NG;                              // NG
  float* xC   = ws + 2*NG;                            // NG
  float* xps  = ws;                                   // reuse [0,3NG) after k_beta2
  float* outf = ws + 3*NG;                            // BLD
  float* outb = outf + BLD;                           // BLD
  float* cpad = outb + BLD;                           // BLD
  int*   tokmap = (int*)(cpad + BLD);                 // B*L
  float* tabf = (float*)(tokmap + (size_t)B*L);       // 3840
  float* tabb = tabf + NBIN*G3;                       // 3840
  float* zl   = tabb + NBIN*G3;                       // B*D
  unsigned short* zhi = (unsigned short*)(zl + (size_t)B*D);  // 1024*128 shorts (packed A)
  unsigned short* zlo = zhi + 1024*128;               // 1024*128 shorts
  int* off    = (int*)(zlo + 1024*128);               // NN+1
  int* cursor = off + NN + 1;                         // NN
  int* csrs   = cursor + NN;                          // NE
  float* csrw = (float*)(csrs + NE);                  // NE
  unsigned short* ehp = (unsigned short*)(csrw + NE); // dedicated packed emb (~25.6MB)
  unsigned short* elp = ehp + (size_t)nslots*8;       // ~25.6MB

  // 1) prep: tables + h0 init + cpad zero + tokmap=-1 + packed-A zero
  hipLaunchKernelGGL(k_prep, dim3(2048), dim3(256), 0, stream,
                     bin_emb, Wih_f, bih_f, Wih_b, bih_b, item_emb, items,
                     tabf, tabb, accA, xB, cpad, tokmap, zhi, zlo,
                     (long long)NG, (long long)BLD, B*L);
  // 2) CSR build: count+scan (single block, deg in LDS) -> fill
  hipLaunchKernelGGL(k_csr1, dim3(1), dim3(1024), 0, stream, edge+NE, off, cursor, NN, NE);
  hipLaunchKernelGGL(k_fill, dim3((NE+255)/256), dim3(256), 0, stream,
                     edge, edge+NE, ew, cursor, csrs, csrw, NE);
  // 3) GCN: 3 gather layers (no atomics, fused accum)
  const int ggrid = (int)((NG + 255)/256);
  hipLaunchKernelGGL(k_gath, dim3(ggrid), dim3(256), 0, stream, xB, xC, accA, off, csrs, csrw, (int)NG);
  hipLaunchKernelGGL(k_gath, dim3(ggrid), dim3(256), 0, stream, xC, xB, accA, off, csrs, csrw, (int)NG);
  hipLaunchKernelGGL(k_gath, dim3(ggrid), dim3(256), 0, stream, xB, xC, accA, off, csrs, csrw, (int)NG);
  // 4) bidirectional GRU (fragment-local MFMA, dbuf h, split chains)
  hipLaunchKernelGGL(k_gru_fb, dim3((B+15)/16, 2), dim3(512), 0, stream,
                     Whh_f, Whh_b, bhh_f, bhh_b, tabf, tabb, bins, B, outf, outb);
  // 5) fused e_hat/beta/c (MFMA)
  hipLaunchKernelGGL(k_beta2, dim3(256), dim3(512), 0, stream,
                     outf, outb, accA, item2idx, w1, w2, v3, seg, pos, T, cpad, tokmap);
  // 6) xps for short GRU (MFMA) + fused z_long
  hipLaunchKernelGGL(k_xps2, dim3(256), dim3(512), 0, stream,
                     cpad, seg, pos, Wih_s, bih_s, T, xps, zl, B);
  // 7) short GRU + final gate -> packed zhi/zlo; idle blocks pack item_emb
  {
    int nGru = (B + 15)/16;              // 63
    hipLaunchKernelGGL(k_grus, dim3(256), dim3(512), 0, stream,
                       Whh_s, bhh_s, bih_s, xps, tokmap, zl, w3, b3, B, zhi, zlo,
                       item_emb, ehp, elp, NI, nslots, nGru);
  }
  // 8) out = z @ emb.T
  {
    int mtiles = (B + FBM - 1)/FBM;      // 8
    hipLaunchKernelGGL(k_fmm, dim3(mtiles*ntilesN), dim3(256), 0, stream,
                       zhi, zlo, ehp, elp, out, NI, B);
  }
}